// Round 6
// baseline (3551.159 us; speedup 1.0000x reference)
//
#include <hip/hip_runtime.h>
#include <hip/hip_bf16.h>

// GRU T=1024 B=64 I=256 H=256.
// d_in order: X, W_fx, W_fg, b_fg, W_ix, W_ig, b_ig, W_ux, W_ug, b_ug (all f32)
// d_out: outs [T,B,H] f32 then h_last [B,H] f32.

typedef _Float16 h2 __attribute__((ext_vector_type(2)));
typedef short bf16x8 __attribute__((ext_vector_type(8)));
typedef float f32x4 __attribute__((ext_vector_type(4)));
typedef unsigned short u16;
typedef unsigned int u32;

union UQ { uint4 u; h2 h[4]; };
union UW { u32 u; h2 h; };

#if __has_builtin(__builtin_amdgcn_fdot2)
#define FDOT2(a, b, c) __builtin_amdgcn_fdot2((a), (b), (c), false)
#else
static __device__ inline float FDOT2(h2 a, h2 b, float c) {
    return c + (float)a[0] * (float)b[0] + (float)a[1] * (float)b[1];
}
#endif

__device__ inline u16 f2bf(float f) {
    u32 u = __float_as_uint(f);
    u = (u + 0x7FFF + ((u >> 16) & 1)) >> 16;   // RNE
    return (u16)u;
}

// Opaque pin: keeps loaded weight values' origin invisible so LLVM cannot
// re-sink the loads into the loop.
__device__ inline void pin(h2& x) { asm volatile("" : "+v"(x)); }

// Raw workgroup barrier: LDS-visibility only, no vmcnt drain (global
// loads/stores here are thread-private and may stay in flight).
__device__ inline void wg_barrier() {
    asm volatile("s_waitcnt lgkmcnt(0)" ::: "memory");
    __builtin_amdgcn_s_barrier();
    asm volatile("" ::: "memory");
}

// ---------------- prep: WcatT [768][256] bf16: WcatT[g*256+j][k] = Wgx[k][j]
__global__ void prep_wcat(const float* __restrict__ Wfx, const float* __restrict__ Wix,
                          const float* __restrict__ Wux, u16* __restrict__ WcatT) {
    int n = blockIdx.x;            // 0..767
    int k = threadIdx.x;           // 0..255
    int g = n >> 8, j = n & 255;
    const float* W = (g == 0) ? Wfx : (g == 1) ? Wix : Wux;
    WcatT[(size_t)n * 256 + k] = f2bf(W[(size_t)k * 256 + j]);
}

// ---------------- prep: WT f16 [3][256][256]: WT[g][j][i] = Wg[i][j] + bg[j]
__global__ void prep_wrec(const float* __restrict__ Wfg, const float* __restrict__ bfg,
                          const float* __restrict__ Wig, const float* __restrict__ big,
                          const float* __restrict__ Wug, const float* __restrict__ bug,
                          _Float16* __restrict__ WT) {
    int n = blockIdx.x;            // 0..767
    int i = threadIdx.x;           // 0..255
    int g = n >> 8, j = n & 255;
    const float* W = (g == 0) ? Wfg : (g == 1) ? Wig : Wug;
    const float* bv = (g == 0) ? bfg : (g == 1) ? big : bug;
    WT[(size_t)n * 256 + i] = (_Float16)(W[(size_t)i * 256 + j] + bv[j]);
}

// ---------------- projection GEMM: proj[65536][768] f16 = X[65536][256] @ Wcat[256][768]
__global__ __launch_bounds__(256) void proj_gemm(const float* __restrict__ X,
                                                 const u16* __restrict__ WT, // WcatT [768][256]
                                                 _Float16* __restrict__ proj) {
    __shared__ u16 shA[128][32];
    __shared__ u16 shB[128][32];
    __shared__ _Float16 shC[128][128];

    int tid = threadIdx.x;
    int bn = blockIdx.x % 6, bm = blockIdx.x / 6;
    int lane = tid & 63, wv = tid >> 6;
    int wr = wv >> 1, wc = wv & 1;

    f32x4 acc[4][4];
#pragma unroll
    for (int m = 0; m < 4; m++)
#pragma unroll
        for (int n = 0; n < 4; n++) acc[m][n] = (f32x4){0.f, 0.f, 0.f, 0.f};

    for (int kt = 0; kt < 8; ++kt) {
#pragma unroll
        for (int q = 0; q < 4; ++q) {
            int g = tid + 256 * q;
            int r = g >> 3, c4 = g & 7;
            const float4 v = *(const float4*)(X + (size_t)(bm * 128 + r) * 256 + kt * 32 + c4 * 4);
            ushort4 o;
            o.x = f2bf(v.x); o.y = f2bf(v.y); o.z = f2bf(v.z); o.w = f2bf(v.w);
            *(ushort4*)&shA[r][c4 * 4] = o;
        }
#pragma unroll
        for (int q = 0; q < 2; ++q) {
            int g = tid + 256 * q;
            int r = g >> 2, c8 = g & 3;
            uint4 v = *(const uint4*)(WT + (size_t)(bn * 128 + r) * 256 + kt * 32 + c8 * 8);
            *(uint4*)&shB[r][c8 * 8] = v;
        }
        __syncthreads();

        bf16x8 af[4], bfr[4];
#pragma unroll
        for (int m = 0; m < 4; m++)
            af[m] = *(const bf16x8*)&shA[wr * 64 + m * 16 + (lane & 15)][(lane >> 4) * 8];
#pragma unroll
        for (int n = 0; n < 4; n++)
            bfr[n] = *(const bf16x8*)&shB[wc * 64 + n * 16 + (lane & 15)][(lane >> 4) * 8];
#pragma unroll
        for (int m = 0; m < 4; m++)
#pragma unroll
            for (int n = 0; n < 4; n++)
                acc[m][n] = __builtin_amdgcn_mfma_f32_16x16x32_bf16(af[m], bfr[n], acc[m][n], 0, 0, 0);
        __syncthreads();
    }

#pragma unroll
    for (int m = 0; m < 4; m++)
#pragma unroll
        for (int n = 0; n < 4; n++)
#pragma unroll
            for (int r = 0; r < 4; r++) {
                int row = wr * 64 + m * 16 + (lane >> 4) * 4 + r;
                int col = wc * 64 + n * 16 + (lane & 15);
                shC[row][col] = (_Float16)acc[m][n][r];
            }
    __syncthreads();
    {
        int row = tid >> 1, hf = tid & 1;
        size_t gbase = (size_t)(bm * 128 + row) * 768 + bn * 128 + hf * 64;
        const uint4* src = (const uint4*)&shC[row][hf * 64];
        uint4* dst = (uint4*)(proj + gbase);
#pragma unroll
        for (int q = 0; q < 8; q++) dst[q] = src[q];
    }
}

// ---------------- recurrence: 64 WGs (one per batch), 256 threads (one per
// column j). Weight residency split across the CU's two on-chip stores:
//   - u-gate (256x256 f16 = 128 KB) -> LDS, transposed [k2][j] u32 layout:
//     reads are stride-4B across lanes (2-way aliasing = free).
//   - f,i-gate -> 256 pinned h2 VGPRs/thread.
// 256 threads = 4 waves = exactly 1 wave/SIMD; amdgpu_waves_per_eu(1,1)
// forces the RA's occupancy target to 1 -> ~512-VGPR budget (m08: no spill
// through 450). Rounds 3-5: any config with >=8 waves/WG got spilled to the
// RA's own budget (116/64) regardless of attributes.
__global__ __attribute__((amdgpu_flat_work_group_size(256, 256)))
__attribute__((amdgpu_waves_per_eu(1, 1)))
void gru_rec(const _Float16* __restrict__ proj,
             const _Float16* __restrict__ WT,
             float* __restrict__ out) {
    int b = blockIdx.x;
    int j = threadIdx.x;

    __shared__ __align__(16) u32 lds_wu[128 * 256];   // [k2][j], 128 KB
    __shared__ __align__(16) _Float16 sh_h[256];      // f16 h (dot operand)
    __shared__ __align__(16) _Float16 sh_rh[256];     // f16 reset*h
    __shared__ __align__(16) float sh_hf[256];        // f32 h (exact state)

    // stage u-gate weights into LDS: lds_wu[k2][j] = u32{WTu[j][2k2], WTu[j][2k2+1]}
    {
        const uint4* pu4 = (const uint4*)(WT + 131072 + (size_t)j * 256);
#pragma unroll
        for (int m = 0; m < 32; m++) {
            uint4 v = pu4[m];
            lds_wu[(4 * m + 0) * 256 + j] = v.x;
            lds_wu[(4 * m + 1) * 256 + j] = v.y;
            lds_wu[(4 * m + 2) * 256 + j] = v.z;
            lds_wu[(4 * m + 3) * 256 + j] = v.w;
        }
    }

    // f,i-gate columns in registers: 2 x 128 h2 = 256 VGPRs
    h2 wf[128], wi[128];
    {
        const uint4* pf = (const uint4*)(WT + (size_t)j * 256);
        const uint4* pi = (const uint4*)(WT + 65536 + (size_t)j * 256);
#pragma unroll
        for (int m = 0; m < 32; m++) {
            UQ a; a.u = pf[m];
            wf[4 * m] = a.h[0]; wf[4 * m + 1] = a.h[1];
            wf[4 * m + 2] = a.h[2]; wf[4 * m + 3] = a.h[3];
        }
#pragma unroll
        for (int m = 0; m < 32; m++) {
            UQ a; a.u = pi[m];
            wi[4 * m] = a.h[0]; wi[4 * m + 1] = a.h[1];
            wi[4 * m + 2] = a.h[2]; wi[4 * m + 3] = a.h[3];
        }
    }
#pragma unroll
    for (int m = 0; m < 128; m++) pin(wf[m]);
#pragma unroll
    for (int m = 0; m < 128; m++) pin(wi[m]);

    sh_h[j] = (_Float16)0.f;
    sh_hf[j] = 0.f;
    __syncthreads();

    const _Float16* prow = proj + (size_t)b * 768 + j;  // step stride 49152 f16
    float xf = (float)prow[0];
    float xi = (float)prow[256];
    float xu = (float)prow[512];
    float* outp = out + (size_t)b * 256 + j;            // step stride 16384 f32
    float hn = 0.f;

    for (int t = 0; t < 1024; ++t) {
        // prefetch next step's x (stays in flight across raw barriers)
        _Float16 r0 = (_Float16)0.f, r1 = (_Float16)0.f, r2 = (_Float16)0.f;
        if (t < 1023) {
            r0 = prow[49152];
            r1 = prow[49152 + 256];
            r2 = prow[49152 + 512];
        }

        float hcur = sh_hf[j];   // stride-4B read, conflict-free

        // phase A: f,i dots over sh_h (uniform-address broadcast b128 reads)
        float f0 = 0.f, f1 = 0.f, f2 = 0.f, f3 = 0.f;
        float i0 = 0.f, i1 = 0.f, i2 = 0.f, i3 = 0.f;
        {
            const uint4* hh = (const uint4*)sh_h;
#pragma unroll
            for (int m = 0; m < 32; m++) {
                UQ a; a.u = hh[m];
                f0 = FDOT2(wf[4 * m],     a.h[0], f0);
                f1 = FDOT2(wf[4 * m + 1], a.h[1], f1);
                i0 = FDOT2(wi[4 * m],     a.h[0], i0);
                i1 = FDOT2(wi[4 * m + 1], a.h[1], i1);
                f2 = FDOT2(wf[4 * m + 2], a.h[2], f2);
                f3 = FDOT2(wf[4 * m + 3], a.h[3], f3);
                i2 = FDOT2(wi[4 * m + 2], a.h[2], i2);
                i3 = FDOT2(wi[4 * m + 3], a.h[3], i3);
            }
        }
        float reset = 1.f / (1.f + __expf(-(xf + (f0 + f1) + (f2 + f3))));
        float upd   = 1.f / (1.f + __expf(-(xi + (i0 + i1) + (i2 + i3))));
        sh_rh[j] = (_Float16)(reset * hcur);

        wg_barrier();   // B1: rh visible (also fences hcur/sh_h reads above)

        // phase B: u dot; weights streamed from LDS (stride-4B, conflict-free),
        // rh via uniform broadcast b128.
        float u0 = 0.f, u1 = 0.f, u2 = 0.f, u3 = 0.f;
        {
            const uint4* rr = (const uint4*)sh_rh;
            const u32* wub = lds_wu + j;
#pragma unroll
            for (int m = 0; m < 32; m++) {
                UQ a; a.u = rr[m];
                UW w0; w0.u = wub[(4 * m + 0) * 256];
                UW w1; w1.u = wub[(4 * m + 1) * 256];
                UW w2; w2.u = wub[(4 * m + 2) * 256];
                UW w3; w3.u = wub[(4 * m + 3) * 256];
                u0 = FDOT2(w0.h, a.h[0], u0);
                u1 = FDOT2(w1.h, a.h[1], u1);
                u2 = FDOT2(w2.h, a.h[2], u2);
                u3 = FDOT2(w3.h, a.h[3], u3);
            }
        }
        float zc = xu + ((u0 + u1) + (u2 + u3));
        float e = __expf(2.f * zc);
        float cand = (e - 1.f) / (e + 1.f);              // tanh
        hn = upd * hcur + (1.f - upd) * cand;

        sh_hf[j] = hn;
        sh_h[j] = (_Float16)hn;
        *outp = hn;                                       // fire-and-forget

        wg_barrier();   // B2: new h visible

        xf = (float)r0; xi = (float)r1; xu = (float)r2;
        prow += 49152;
        outp += 16384;
    }

    out[(size_t)16777216 + (size_t)b * 256 + j] = hn;
}

extern "C" void kernel_launch(void* const* d_in, const int* in_sizes, int n_in,
                              void* d_out, int out_size, void* d_ws, size_t ws_size,
                              hipStream_t stream) {
    const float* X   = (const float*)d_in[0];
    const float* Wfx = (const float*)d_in[1];
    const float* Wfg = (const float*)d_in[2];
    const float* bfg = (const float*)d_in[3];
    const float* Wix = (const float*)d_in[4];
    const float* Wig = (const float*)d_in[5];
    const float* big = (const float*)d_in[6];
    const float* Wux = (const float*)d_in[7];
    const float* Wug = (const float*)d_in[8];
    const float* bug = (const float*)d_in[9];
    float* out = (float*)d_out;

    char* ws = (char*)d_ws;
    _Float16* proj = (_Float16*)ws;                          // 65536*768*2 = 100663296 B
    u16* WcatT = (u16*)(ws + 100663296);                     // 768*256*2   = 393216 B
    _Float16* WT = (_Float16*)(ws + 100663296 + 393216);     // 3*256*256*2 = 393216 B

    prep_wcat<<<768, 256, 0, stream>>>(Wfx, Wix, Wux, WcatT);
    prep_wrec<<<768, 256, 0, stream>>>(Wfg, bfg, Wig, big, Wug, bug, WT);
    proj_gemm<<<3072, 256, 0, stream>>>(X, WcatT, proj);
    gru_rec<<<64, 256, 0, stream>>>(proj, WT, out);
}

// Round 7
// 3200.642 us; speedup vs baseline: 1.1095x; 1.1095x over previous
//
#include <hip/hip_runtime.h>
#include <hip/hip_bf16.h>

// GRU T=1024 B=64 I=256 H=256.
// d_in order: X, W_fx, W_fg, b_fg, W_ix, W_ig, b_ig, W_ux, W_ug, b_ug (all f32)
// d_out: outs [T,B,H] f32 then h_last [B,H] f32.

typedef _Float16 h2 __attribute__((ext_vector_type(2)));
typedef short bf16x8 __attribute__((ext_vector_type(8)));
typedef float f32x4 __attribute__((ext_vector_type(4)));
typedef unsigned short u16;
typedef unsigned int u32;

union UQ { uint4 u; h2 h[4]; };

#if __has_builtin(__builtin_amdgcn_fdot2)
#define FDOT2(a, b, c) __builtin_amdgcn_fdot2((a), (b), (c), false)
#else
static __device__ inline float FDOT2(h2 a, h2 b, float c) {
    return c + (float)a[0] * (float)b[0] + (float)a[1] * (float)b[1];
}
#endif

__device__ inline u16 f2bf(float f) {
    u32 u = __float_as_uint(f);
    u = (u + 0x7FFF + ((u >> 16) & 1)) >> 16;   // RNE
    return (u16)u;
}

// Register pins. A wave can address only 256 VGPRs (v0-v255) but gfx950's
// unified file gives another 256 AGPRs (a0-a255) at 1 wave/SIMD. Weights:
// 384 h2 total -> 128 in VGPRs ("+v") + 256 in AGPRs ("+a"). VALU on CDNA2+
// can source AGPRs (else compiler inserts full-rate v_accvgpr_read copies).
__device__ inline void pinv(h2& x) { asm volatile("" : "+v"(x)); }
__device__ inline void pina(h2& x) { asm volatile("" : "+a"(x)); }

// Raw workgroup barrier: LDS-visibility only, no vmcnt drain (global
// loads/stores here are thread-private and may stay in flight).
__device__ inline void wg_barrier() {
    asm volatile("s_waitcnt lgkmcnt(0)" ::: "memory");
    __builtin_amdgcn_s_barrier();
    asm volatile("" ::: "memory");
}

// ---------------- prep: WcatT [768][256] bf16: WcatT[g*256+j][k] = Wgx[k][j]
__global__ void prep_wcat(const float* __restrict__ Wfx, const float* __restrict__ Wix,
                          const float* __restrict__ Wux, u16* __restrict__ WcatT) {
    int n = blockIdx.x;            // 0..767
    int k = threadIdx.x;           // 0..255
    int g = n >> 8, j = n & 255;
    const float* W = (g == 0) ? Wfx : (g == 1) ? Wix : Wux;
    WcatT[(size_t)n * 256 + k] = f2bf(W[(size_t)k * 256 + j]);
}

// ---------------- prep: WT f16 [3][256][256]: WT[g][j][i] = Wg[i][j] + bg[j]
__global__ void prep_wrec(const float* __restrict__ Wfg, const float* __restrict__ bfg,
                          const float* __restrict__ Wig, const float* __restrict__ big,
                          const float* __restrict__ Wug, const float* __restrict__ bug,
                          _Float16* __restrict__ WT) {
    int n = blockIdx.x;            // 0..767
    int i = threadIdx.x;           // 0..255
    int g = n >> 8, j = n & 255;
    const float* W = (g == 0) ? Wfg : (g == 1) ? Wig : Wug;
    const float* bv = (g == 0) ? bfg : (g == 1) ? big : bug;
    WT[(size_t)n * 256 + i] = (_Float16)(W[(size_t)i * 256 + j] + bv[j]);
}

// ---------------- projection GEMM: proj[65536][768] f16 = X[65536][256] @ Wcat[256][768]
__global__ __launch_bounds__(256) void proj_gemm(const float* __restrict__ X,
                                                 const u16* __restrict__ WT, // WcatT [768][256]
                                                 _Float16* __restrict__ proj) {
    __shared__ u16 shA[128][32];
    __shared__ u16 shB[128][32];
    __shared__ _Float16 shC[128][128];

    int tid = threadIdx.x;
    int bn = blockIdx.x % 6, bm = blockIdx.x / 6;
    int lane = tid & 63, wv = tid >> 6;
    int wr = wv >> 1, wc = wv & 1;

    f32x4 acc[4][4];
#pragma unroll
    for (int m = 0; m < 4; m++)
#pragma unroll
        for (int n = 0; n < 4; n++) acc[m][n] = (f32x4){0.f, 0.f, 0.f, 0.f};

    for (int kt = 0; kt < 8; ++kt) {
#pragma unroll
        for (int q = 0; q < 4; ++q) {
            int g = tid + 256 * q;
            int r = g >> 3, c4 = g & 7;
            const float4 v = *(const float4*)(X + (size_t)(bm * 128 + r) * 256 + kt * 32 + c4 * 4);
            ushort4 o;
            o.x = f2bf(v.x); o.y = f2bf(v.y); o.z = f2bf(v.z); o.w = f2bf(v.w);
            *(ushort4*)&shA[r][c4 * 4] = o;
        }
#pragma unroll
        for (int q = 0; q < 2; ++q) {
            int g = tid + 256 * q;
            int r = g >> 2, c8 = g & 3;
            uint4 v = *(const uint4*)(WT + (size_t)(bn * 128 + r) * 256 + kt * 32 + c8 * 8);
            *(uint4*)&shB[r][c8 * 8] = v;
        }
        __syncthreads();

        bf16x8 af[4], bfr[4];
#pragma unroll
        for (int m = 0; m < 4; m++)
            af[m] = *(const bf16x8*)&shA[wr * 64 + m * 16 + (lane & 15)][(lane >> 4) * 8];
#pragma unroll
        for (int n = 0; n < 4; n++)
            bfr[n] = *(const bf16x8*)&shB[wc * 64 + n * 16 + (lane & 15)][(lane >> 4) * 8];
#pragma unroll
        for (int m = 0; m < 4; m++)
#pragma unroll
            for (int n = 0; n < 4; n++)
                acc[m][n] = __builtin_amdgcn_mfma_f32_16x16x32_bf16(af[m], bfr[n], acc[m][n], 0, 0, 0);
        __syncthreads();
    }

#pragma unroll
    for (int m = 0; m < 4; m++)
#pragma unroll
        for (int n = 0; n < 4; n++)
#pragma unroll
            for (int r = 0; r < 4; r++) {
                int row = wr * 64 + m * 16 + (lane >> 4) * 4 + r;
                int col = wc * 64 + n * 16 + (lane & 15);
                shC[row][col] = (_Float16)acc[m][n][r];
            }
    __syncthreads();
    {
        int row = tid >> 1, hf = tid & 1;
        size_t gbase = (size_t)(bm * 128 + row) * 768 + bn * 128 + hf * 64;
        const uint4* src = (const uint4*)&shC[row][hf * 64];
        uint4* dst = (uint4*)(proj + gbase);
#pragma unroll
        for (int q = 0; q < 8; q++) dst[q] = src[q];
    }
}

// ---------------- recurrence: 64 WGs (one per batch), 256 threads (one per
// column j), 4 waves = 1 wave/SIMD. All 384 weight h2 on-chip per thread:
//   wf (128 h2) -> VGPRs;  wi, wu (256 h2) -> AGPRs (unified file overflow).
// VGPR demand ~180 < 256 arch cap; AGPR demand = 256 = cap. Total 430 < 512
// regs/lane available at 1 wave/SIMD.
__global__ __attribute__((amdgpu_flat_work_group_size(256, 256)))
__attribute__((amdgpu_waves_per_eu(1, 1)))
void gru_rec(const _Float16* __restrict__ proj,
             const _Float16* __restrict__ WT,
             float* __restrict__ out) {
    int b = blockIdx.x;
    int j = threadIdx.x;

    __shared__ __align__(16) _Float16 sh_h[256];      // f16 h (dot operand)
    __shared__ __align__(16) _Float16 sh_rh[256];     // f16 reset*h
    __shared__ __align__(16) float sh_hf[256];        // f32 h (exact state)

    h2 wf[128], wi[128], wu[128];
    {
        const uint4* pf = (const uint4*)(WT + (size_t)j * 256);
        const uint4* pi = (const uint4*)(WT + 65536 + (size_t)j * 256);
        const uint4* pu = (const uint4*)(WT + 131072 + (size_t)j * 256);
#pragma unroll
        for (int m = 0; m < 32; m++) {
            UQ a; a.u = pf[m];
            wf[4 * m] = a.h[0]; wf[4 * m + 1] = a.h[1];
            wf[4 * m + 2] = a.h[2]; wf[4 * m + 3] = a.h[3];
        }
#pragma unroll
        for (int m = 0; m < 32; m++) {
            UQ a; a.u = pi[m];
            wi[4 * m] = a.h[0]; wi[4 * m + 1] = a.h[1];
            wi[4 * m + 2] = a.h[2]; wi[4 * m + 3] = a.h[3];
        }
#pragma unroll
        for (int m = 0; m < 32; m++) {
            UQ a; a.u = pu[m];
            wu[4 * m] = a.h[0]; wu[4 * m + 1] = a.h[1];
            wu[4 * m + 2] = a.h[2]; wu[4 * m + 3] = a.h[3];
        }
    }
#pragma unroll
    for (int m = 0; m < 128; m++) pinv(wf[m]);
#pragma unroll
    for (int m = 0; m < 128; m++) pina(wi[m]);
#pragma unroll
    for (int m = 0; m < 128; m++) pina(wu[m]);

    sh_h[j] = (_Float16)0.f;
    sh_hf[j] = 0.f;
    __syncthreads();

    const _Float16* prow = proj + (size_t)b * 768 + j;  // step stride 49152 f16
    float xf = (float)prow[0];
    float xi = (float)prow[256];
    float xu = (float)prow[512];
    float* outp = out + (size_t)b * 256 + j;            // step stride 16384 f32
    float hn = 0.f;

    for (int t = 0; t < 1024; ++t) {
        // prefetch next step's x (stays in flight across raw barriers)
        _Float16 r0 = (_Float16)0.f, r1 = (_Float16)0.f, r2 = (_Float16)0.f;
        if (t < 1023) {
            r0 = prow[49152];
            r1 = prow[49152 + 256];
            r2 = prow[49152 + 512];
        }

        float hcur = sh_hf[j];   // stride-4B read, conflict-free

        // phase A: f,i dots over sh_h (uniform-address broadcast b128 reads)
        float f0 = 0.f, f1 = 0.f, f2 = 0.f, f3 = 0.f;
        float i0 = 0.f, i1 = 0.f, i2 = 0.f, i3 = 0.f;
        {
            const uint4* hh = (const uint4*)sh_h;
#pragma unroll
            for (int m = 0; m < 32; m++) {
                UQ a; a.u = hh[m];
                f0 = FDOT2(wf[4 * m],     a.h[0], f0);
                f1 = FDOT2(wf[4 * m + 1], a.h[1], f1);
                i0 = FDOT2(wi[4 * m],     a.h[0], i0);
                i1 = FDOT2(wi[4 * m + 1], a.h[1], i1);
                f2 = FDOT2(wf[4 * m + 2], a.h[2], f2);
                f3 = FDOT2(wf[4 * m + 3], a.h[3], f3);
                i2 = FDOT2(wi[4 * m + 2], a.h[2], i2);
                i3 = FDOT2(wi[4 * m + 3], a.h[3], i3);
            }
        }
        float reset = 1.f / (1.f + __expf(-(xf + (f0 + f1) + (f2 + f3))));
        float upd   = 1.f / (1.f + __expf(-(xi + (i0 + i1) + (i2 + i3))));
        sh_rh[j] = (_Float16)(reset * hcur);

        wg_barrier();   // B1: rh visible

        // phase B: u dot over sh_rh (broadcast b128 reads), weights from AGPRs
        float u0 = 0.f, u1 = 0.f, u2 = 0.f, u3 = 0.f;
        {
            const uint4* rr = (const uint4*)sh_rh;
#pragma unroll
            for (int m = 0; m < 32; m++) {
                UQ a; a.u = rr[m];
                u0 = FDOT2(wu[4 * m],     a.h[0], u0);
                u1 = FDOT2(wu[4 * m + 1], a.h[1], u1);
                u2 = FDOT2(wu[4 * m + 2], a.h[2], u2);
                u3 = FDOT2(wu[4 * m + 3], a.h[3], u3);
            }
        }
        float zc = xu + ((u0 + u1) + (u2 + u3));
        float e = __expf(2.f * zc);
        float cand = (e - 1.f) / (e + 1.f);              // tanh
        hn = upd * hcur + (1.f - upd) * cand;

        sh_hf[j] = hn;
        sh_h[j] = (_Float16)hn;
        *outp = hn;                                       // fire-and-forget

        wg_barrier();   // B2: new h visible

        xf = (float)r0; xi = (float)r1; xu = (float)r2;
        prow += 49152;
        outp += 16384;
    }

    out[(size_t)16777216 + (size_t)b * 256 + j] = hn;
}

extern "C" void kernel_launch(void* const* d_in, const int* in_sizes, int n_in,
                              void* d_out, int out_size, void* d_ws, size_t ws_size,
                              hipStream_t stream) {
    const float* X   = (const float*)d_in[0];
    const float* Wfx = (const float*)d_in[1];
    const float* Wfg = (const float*)d_in[2];
    const float* bfg = (const float*)d_in[3];
    const float* Wix = (const float*)d_in[4];
    const float* Wig = (const float*)d_in[5];
    const float* big = (const float*)d_in[6];
    const float* Wux = (const float*)d_in[7];
    const float* Wug = (const float*)d_in[8];
    const float* bug = (const float*)d_in[9];
    float* out = (float*)d_out;

    char* ws = (char*)d_ws;
    _Float16* proj = (_Float16*)ws;                          // 65536*768*2 = 100663296 B
    u16* WcatT = (u16*)(ws + 100663296);                     // 768*256*2   = 393216 B
    _Float16* WT = (_Float16*)(ws + 100663296 + 393216);     // 3*256*256*2 = 393216 B

    prep_wcat<<<768, 256, 0, stream>>>(Wfx, Wix, Wux, WcatT);
    prep_wrec<<<768, 256, 0, stream>>>(Wfg, bfg, Wig, big, Wug, bug, WT);
    proj_gemm<<<3072, 256, 0, stream>>>(X, WcatT, proj);
    gru_rec<<<64, 256, 0, stream>>>(proj, WT, out);
}

// Round 8
// 2473.067 us; speedup vs baseline: 1.4359x; 1.2942x over previous
//
#include <hip/hip_runtime.h>
#include <hip/hip_bf16.h>

// GRU T=1024 B=64 I=256 H=256.
// d_in order: X, W_fx, W_fg, b_fg, W_ix, W_ig, b_ig, W_ux, W_ug, b_ug (all f32)
// d_out: outs [T,B,H] f32 then h_last [B,H] f32.

typedef _Float16 f16x4 __attribute__((ext_vector_type(4)));
typedef _Float16 f16x8 __attribute__((ext_vector_type(8)));
typedef float f32x4 __attribute__((ext_vector_type(4)));
typedef unsigned short u16;
typedef unsigned int u32;

__device__ inline u16 f2bf(float f) {
    u32 u = __float_as_uint(f);
    u = (u + 0x7FFF + ((u >> 16) & 1)) >> 16;   // RNE
    return (u16)u;
}

// MFMA is the one unit that legitimately consumes AGPRs: pin weight
// fragments there ("+a"); wu stays VGPR ("+v"). Pins also stop LLVM from
// re-sinking the loads into the loop.
__device__ inline void pinA(f16x8& x) { asm volatile("" : "+a"(x)); }
__device__ inline void pinV(f16x8& x) { asm volatile("" : "+v"(x)); }

// Raw workgroup barrier: LDS-visibility only, no vmcnt drain (global
// loads/stores here are thread-private and may stay in flight).
__device__ inline void wg_barrier() {
    asm volatile("s_waitcnt lgkmcnt(0)" ::: "memory");
    __builtin_amdgcn_s_barrier();
    asm volatile("" ::: "memory");
}

// ---------------- prep: WcatT [768][256] bf16: WcatT[g*256+j][k] = Wgx[k][j]
__global__ void prep_wcat(const float* __restrict__ Wfx, const float* __restrict__ Wix,
                          const float* __restrict__ Wux, u16* __restrict__ WcatT) {
    int n = blockIdx.x;            // 0..767
    int k = threadIdx.x;           // 0..255
    int g = n >> 8, j = n & 255;
    const float* W = (g == 0) ? Wfx : (g == 1) ? Wix : Wux;
    WcatT[(size_t)n * 256 + k] = f2bf(W[(size_t)k * 256 + j]);
}

// ---------------- prep: WT f16 [3][256][256]: WT[g][j][i] = Wg[i][j] + bg[j]
__global__ void prep_wrec(const float* __restrict__ Wfg, const float* __restrict__ bfg,
                          const float* __restrict__ Wig, const float* __restrict__ big,
                          const float* __restrict__ Wug, const float* __restrict__ bug,
                          _Float16* __restrict__ WT) {
    int n = blockIdx.x;            // 0..767
    int i = threadIdx.x;           // 0..255
    int g = n >> 8, j = n & 255;
    const float* W = (g == 0) ? Wfg : (g == 1) ? Wig : Wug;
    const float* bv = (g == 0) ? bfg : (g == 1) ? big : bug;
    WT[(size_t)n * 256 + i] = (_Float16)(W[(size_t)i * 256 + j] + bv[j]);
}

// ---------------- projection GEMM: proj[65536][768] f16 = X[65536][256] @ Wcat[256][768]
typedef short bf16x8 __attribute__((ext_vector_type(8)));
__global__ __launch_bounds__(256) void proj_gemm(const float* __restrict__ X,
                                                 const u16* __restrict__ WT, // WcatT [768][256]
                                                 _Float16* __restrict__ proj) {
    __shared__ u16 shA[128][32];
    __shared__ u16 shB[128][32];
    __shared__ _Float16 shC[128][128];

    int tid = threadIdx.x;
    int bn = blockIdx.x % 6, bm = blockIdx.x / 6;
    int lane = tid & 63, wv = tid >> 6;
    int wr = wv >> 1, wc = wv & 1;

    f32x4 acc[4][4];
#pragma unroll
    for (int m = 0; m < 4; m++)
#pragma unroll
        for (int n = 0; n < 4; n++) acc[m][n] = (f32x4){0.f, 0.f, 0.f, 0.f};

    for (int kt = 0; kt < 8; ++kt) {
#pragma unroll
        for (int q = 0; q < 4; ++q) {
            int g = tid + 256 * q;
            int r = g >> 3, c4 = g & 7;
            const float4 v = *(const float4*)(X + (size_t)(bm * 128 + r) * 256 + kt * 32 + c4 * 4);
            ushort4 o;
            o.x = f2bf(v.x); o.y = f2bf(v.y); o.z = f2bf(v.z); o.w = f2bf(v.w);
            *(ushort4*)&shA[r][c4 * 4] = o;
        }
#pragma unroll
        for (int q = 0; q < 2; ++q) {
            int g = tid + 256 * q;
            int r = g >> 2, c8 = g & 3;
            uint4 v = *(const uint4*)(WT + (size_t)(bn * 128 + r) * 256 + kt * 32 + c8 * 8);
            *(uint4*)&shB[r][c8 * 8] = v;
        }
        __syncthreads();

        bf16x8 af[4], bfr[4];
#pragma unroll
        for (int m = 0; m < 4; m++)
            af[m] = *(const bf16x8*)&shA[wr * 64 + m * 16 + (lane & 15)][(lane >> 4) * 8];
#pragma unroll
        for (int n = 0; n < 4; n++)
            bfr[n] = *(const bf16x8*)&shB[wc * 64 + n * 16 + (lane & 15)][(lane >> 4) * 8];
#pragma unroll
        for (int m = 0; m < 4; m++)
#pragma unroll
            for (int n = 0; n < 4; n++)
                acc[m][n] = __builtin_amdgcn_mfma_f32_16x16x32_bf16(af[m], bfr[n], acc[m][n], 0, 0, 0);
        __syncthreads();
    }

#pragma unroll
    for (int m = 0; m < 4; m++)
#pragma unroll
        for (int n = 0; n < 4; n++)
#pragma unroll
            for (int r = 0; r < 4; r++) {
                int row = wr * 64 + m * 16 + (lane >> 4) * 4 + r;
                int col = wc * 64 + n * 16 + (lane & 15);
                shC[row][col] = (_Float16)acc[m][n][r];
            }
    __syncthreads();
    {
        int row = tid >> 1, hf = tid & 1;
        size_t gbase = (size_t)(bm * 128 + row) * 768 + bn * 128 + hf * 64;
        const uint4* src = (const uint4*)&shC[row][hf * 64];
        uint4* dst = (uint4*)(proj + gbase);
#pragma unroll
        for (int q = 0; q < 8; q++) dst[q] = src[q];
    }
}

// ---------------- MFMA recurrence: 4 WGs x 16 batches, 256 threads (4 waves,
// 1 wave/SIMD). Transposed product D' = W^T * h^T per gate:
//   A-frag = WT[g][j][k-contig8]  (weights; wf,wi in AGPR, wu in VGPR)
//   B-frag = h16[m=lane&15][k-contig8]  (LDS, row-major, +8 pad)
//   D'    : col = lane&15 = batch m, row = (lane>>4)*4+reg = j-in-tile
// => per-lane output (m fixed, j contiguous): b64 LDS writes, dwordx2 x-loads,
//    dwordx4 out-stores. 2 raw barriers/step. f32 state in regs.
__global__ __attribute__((amdgpu_flat_work_group_size(256, 256)))
__attribute__((amdgpu_waves_per_eu(1, 1)))
void gru_rec(const _Float16* __restrict__ proj,
             const _Float16* __restrict__ WT,
             float* __restrict__ out) {
    const int tid = threadIdx.x;
    const int wg = blockIdx.x;              // batches [wg*16, wg*16+16)
    const int l = tid & 63, w = tid >> 6;   // wave w owns cols [w*64, w*64+64)
    const int lo = l & 15, hi = l >> 4;

    __shared__ _Float16 h16[16][264];       // h (f16), row m, +8 pad
    __shared__ _Float16 rh16[16][264];      // reset*h

    for (int idx = tid; idx < 16 * 264; idx += 256) {
        (&h16[0][0])[idx]  = (_Float16)0.f;
        (&rh16[0][0])[idx] = (_Float16)0.f;
    }

    // weight fragments: frag(g,jt,kt)[e] = WT[g][w*64+jt*16+lo][kt*32+hi*8+e]
    f16x8 wfA[32], wiA[32], wuV[32];
    {
        const _Float16* base = WT + ((size_t)w * 64 + lo) * 256 + hi * 8;
#pragma unroll
        for (int jt = 0; jt < 4; ++jt)
#pragma unroll
            for (int kt = 0; kt < 8; ++kt) {
                size_t off = (size_t)jt * 16 * 256 + (size_t)kt * 32;
                wfA[jt * 8 + kt] = *(const f16x8*)(base + off);
                wiA[jt * 8 + kt] = *(const f16x8*)(base + 65536 + off);
                wuV[jt * 8 + kt] = *(const f16x8*)(base + 131072 + off);
            }
    }
#pragma unroll
    for (int m = 0; m < 32; ++m) { pinA(wfA[m]); pinA(wiA[m]); pinV(wuV[m]); }

    float hreg[4][4];                       // h[m=lo][j = w*64+jt*16+hi*4+r]
#pragma unroll
    for (int jt = 0; jt < 4; ++jt)
#pragma unroll
        for (int r = 0; r < 4; ++r) hreg[jt][r] = 0.f;
    float upd[4][4];

    // x element (g,jt,r) = proj[(t*64+wg*16+lo)*768 + g*256 + w*64+jt*16+hi*4+r]
    const _Float16* xbase = proj + ((size_t)wg * 16 + lo) * 768 + w * 64 + hi * 4;
    f16x4 xf4[4], xi4[4], xu4[4];
#pragma unroll
    for (int jt = 0; jt < 4; ++jt) {
        xf4[jt] = *(const f16x4*)(xbase + jt * 16);
        xi4[jt] = *(const f16x4*)(xbase + 256 + jt * 16);
        xu4[jt] = *(const f16x4*)(xbase + 512 + jt * 16);
    }

    float* obase = out + ((size_t)wg * 16 + lo) * 256 + w * 64 + hi * 4;

    __syncthreads();

    for (int t = 0; t < 1024; ++t) {
        // ---- phase F/I: accF = Wf^T h^T, accI = Wi^T h^T
        f32x4 accF[4], accI[4];
#pragma unroll
        for (int jt = 0; jt < 4; ++jt) {
            accF[jt] = (f32x4){0.f, 0.f, 0.f, 0.f};
            accI[jt] = (f32x4){0.f, 0.f, 0.f, 0.f};
        }
#pragma unroll
        for (int kh = 0; kh < 2; ++kh) {
            f16x8 hb[4];
#pragma unroll
            for (int q = 0; q < 4; ++q)
                hb[q] = *(const f16x8*)&h16[lo][(kh * 4 + q) * 32 + hi * 8];
#pragma unroll
            for (int q = 0; q < 4; ++q) {
                const int kt = kh * 4 + q;
#pragma unroll
                for (int jt = 0; jt < 4; ++jt) {
                    accF[jt] = __builtin_amdgcn_mfma_f32_16x16x32_f16(wfA[jt * 8 + kt], hb[q], accF[jt], 0, 0, 0);
                    accI[jt] = __builtin_amdgcn_mfma_f32_16x16x32_f16(wiA[jt * 8 + kt], hb[q], accI[jt], 0, 0, 0);
                }
            }
        }
        // reset/update sigmoids; write rh (one b64 per jt)
#pragma unroll
        for (int jt = 0; jt < 4; ++jt) {
            f16x4 rhv;
#pragma unroll
            for (int r = 0; r < 4; ++r) {
                float zf = (float)xf4[jt][r] + accF[jt][r];
                float zi = (float)xi4[jt][r] + accI[jt][r];
                float reset = __builtin_amdgcn_rcpf(1.f + __expf(-zf));
                upd[jt][r]  = __builtin_amdgcn_rcpf(1.f + __expf(-zi));
                rhv[r] = (_Float16)(reset * hreg[jt][r]);
            }
            *(f16x4*)&rh16[lo][w * 64 + jt * 16 + hi * 4] = rhv;
        }
        // prefetch next-step xf, xi (just consumed; covered by U + next F)
        {
            const _Float16* nb = xbase + (size_t)(t + 1) * 49152;
#pragma unroll
            for (int jt = 0; jt < 4; ++jt) {
                xf4[jt] = *(const f16x4*)(nb + jt * 16);
                xi4[jt] = *(const f16x4*)(nb + 256 + jt * 16);
            }
        }
        wg_barrier();   // B1: rh visible

        // ---- phase U: accU = Wu^T rh^T
        f32x4 accU[4];
#pragma unroll
        for (int jt = 0; jt < 4; ++jt) accU[jt] = (f32x4){0.f, 0.f, 0.f, 0.f};
#pragma unroll
        for (int kh = 0; kh < 2; ++kh) {
            f16x8 rb[4];
#pragma unroll
            for (int q = 0; q < 4; ++q)
                rb[q] = *(const f16x8*)&rh16[lo][(kh * 4 + q) * 32 + hi * 8];
#pragma unroll
            for (int q = 0; q < 4; ++q) {
                const int kt = kh * 4 + q;
#pragma unroll
                for (int jt = 0; jt < 4; ++jt)
                    accU[jt] = __builtin_amdgcn_mfma_f32_16x16x32_f16(wuV[jt * 8 + kt], rb[q], accU[jt], 0, 0, 0);
            }
        }
        // tanh + combine; write h (b64) and out (dwordx4)
        float* op = obase + (size_t)t * 16384;
#pragma unroll
        for (int jt = 0; jt < 4; ++jt) {
            f16x4 hv; f32x4 ov;
#pragma unroll
            for (int r = 0; r < 4; ++r) {
                float zu = (float)xu4[jt][r] + accU[jt][r];
                float e2 = __expf(2.f * zu);
                float cand = (e2 - 1.f) * __builtin_amdgcn_rcpf(e2 + 1.f);
                float hn = upd[jt][r] * hreg[jt][r] + (1.f - upd[jt][r]) * cand;
                hreg[jt][r] = hn;
                hv[r] = (_Float16)hn;
                ov[r] = hn;
            }
            *(f16x4*)&h16[lo][w * 64 + jt * 16 + hi * 4] = hv;
            *(f32x4*)(op + jt * 16) = ov;
        }
        // prefetch next-step xu (just consumed; covered by next F)
        {
            const _Float16* nb = xbase + (size_t)(t + 1) * 49152 + 512;
#pragma unroll
            for (int jt = 0; jt < 4; ++jt) xu4[jt] = *(const f16x4*)(nb + jt * 16);
        }
        wg_barrier();   // B2: h visible
    }

    // h_last
    float* hp = out + (size_t)16777216 + ((size_t)wg * 16 + lo) * 256 + w * 64 + hi * 4;
#pragma unroll
    for (int jt = 0; jt < 4; ++jt) {
        f32x4 hv;
#pragma unroll
        for (int r = 0; r < 4; ++r) hv[r] = hreg[jt][r];
        *(f32x4*)(hp + jt * 16) = hv;
    }
}

extern "C" void kernel_launch(void* const* d_in, const int* in_sizes, int n_in,
                              void* d_out, int out_size, void* d_ws, size_t ws_size,
                              hipStream_t stream) {
    const float* X   = (const float*)d_in[0];
    const float* Wfx = (const float*)d_in[1];
    const float* Wfg = (const float*)d_in[2];
    const float* bfg = (const float*)d_in[3];
    const float* Wix = (const float*)d_in[4];
    const float* Wig = (const float*)d_in[5];
    const float* big = (const float*)d_in[6];
    const float* Wux = (const float*)d_in[7];
    const float* Wug = (const float*)d_in[8];
    const float* bug = (const float*)d_in[9];
    float* out = (float*)d_out;

    char* ws = (char*)d_ws;
    _Float16* proj = (_Float16*)ws;                          // 65536*768*2 = 100663296 B
    u16* WcatT = (u16*)(ws + 100663296);                     // 768*256*2   = 393216 B
    _Float16* WT = (_Float16*)(ws + 100663296 + 393216);     // 3*256*256*2 = 393216 B

    prep_wcat<<<768, 256, 0, stream>>>(Wfx, Wix, Wux, WcatT);
    prep_wrec<<<768, 256, 0, stream>>>(Wfg, bfg, Wig, big, Wug, bug, WT);
    proj_gemm<<<3072, 256, 0, stream>>>(X, WcatT, proj);
    gru_rec<<<4, 256, 0, stream>>>(proj, WT, out);
}